// Round 9
// baseline (1160.824 us; speedup 1.0000x reference)
//
#include <hip/hip_runtime.h>
#include <hip/hip_bf16.h>

// Problem constants (T=2048, B=8, C=512, O=512, RD=64, NE=8, tau=1, commit=0.1)
// Ledger: r8 LDS-conflict fix (no change), r10 XCD B-local (slower), r11
// counted-vmcnt (slower), r14 occupancy (spilled), r15 spill-free occupancy
// (161us, slower: tile halving doubled per-MFMA overhead; occ stayed 25%).
// Full LDS-op accounting: ~125 ds ops/CU/phase (incl 64 sc-scale b128 reads)
// ~1500cyc + barrier vmcnt(0) drain + MFMA 310 = the 4000cyc/phase wall.
// Key realization: LDS provides ~no sharing here (B panels are per-wave
// private; only A shared) -> the gl_lds->barrier->ds_read machinery IS the
// bottleneck, not a fix for it.
// Round-16: ALL-REGISTER streaming GEMM. No operand LDS, no per-phase
// barriers (one total, for sc). B fragments load global->reg directly (the
// MFMA gather pattern = 16 cache lines = same as coalesced); ping-pong reg
// buffers prefetched 1 phase ahead; compiler-managed waitcnt (no asm). A
// gathered+pkt-packed in-register once per kk, reused across 9 experts.
// Tile 256m x 64o, wave 64x64, grid(64,8): same-bx blocks share an XCD ->
// x L2-local; B re-read factor halves (604->302MB). kk-loop unrolled x2 so
// reg ping-pong parity is static (no dynamic-indexed reg arrays).
#define NROWS 16384
#define CC 512
#define OO 512
#define RDIM 64
#define NE 8
#define NEXP 9            // 8 experts + bias_w as expert 8 (scale 1.0)
#define COMMIT_SCALE 0.1f
#define LOG2PI_TERM 58.81206612509905f   // (RD/2)*log(2*pi*tau), tau=1

typedef __attribute__((ext_vector_type(8))) short short8;
typedef __attribute__((ext_vector_type(4))) float f32x4;

__device__ __forceinline__ unsigned short f2bf(float f) {
  unsigned int u = __float_as_uint(f);
  u += 0x7fffu + ((u >> 16) & 1u);   // round-to-nearest-even
  return (unsigned short)(u >> 16);
}
// truncating pack: [hi16(b) | hi16(a)]
__device__ __forceinline__ unsigned int pkt(float a, float b) {
  return (__float_as_uint(b) & 0xffff0000u) | (__float_as_uint(a) >> 16);
}

// ---------------------------------------------------------------------------
// Kernel 0: f32->bf16 copy of [pw_w ; bias_w] -> wb; transpose map_w -> wT4.
// ---------------------------------------------------------------------------
#define P4 524288u    // pw_w float4 count   (2097152 / 4)
#define B4 65536u     // bias_w float4 count (262144 / 4)
#define NCV ((P4 + B4) / 256u)        // 2304 convert blocks
#define TB 128u                        // 32768 map_w elems / 256

__global__ __launch_bounds__(256) void k_prep(
    const float* __restrict__ pw, const float* __restrict__ bw,
    const float* __restrict__ mw,
    unsigned short* __restrict__ wb, float* __restrict__ wT4)
{
  unsigned int b = blockIdx.x;
  if (b >= NCV) {   // map_w transpose: i indexes map_w[j*512+c]
    unsigned int i = (b - NCV) * 256 + threadIdx.x;
    unsigned int j = i >> 9, c = i & 511u;
    wT4[((c >> 2) << 8) + (j << 2) + (c & 3u)] = mw[i];
    return;
  }
  unsigned int i = b * 256 + threadIdx.x;   // float4 index into [pw|bw]
  const float* src = (i < P4) ? (pw + (size_t)i * 4)
                              : (bw + (size_t)(i - P4) * 4);
  unsigned short* dst = wb + (size_t)i * 4;
  float4 v = *(const float4*)src;
  ushort4 o;
  o.x = f2bf(v.x); o.y = f2bf(v.y); o.z = f2bf(v.z); o.w = f2bf(v.w);
  *(ushort4*)dst = o;
}

// ---------------------------------------------------------------------------
// Kernel 1: GMM responsibilities + loss (pure f32).
// ---------------------------------------------------------------------------
__global__ __launch_bounds__(256) void k_assign(
    const float* __restrict__ x,      // [N, C]
    const float* __restrict__ wT4,    // [C/4, 64, 4] transposed map_w
    const float* __restrict__ map_b,  // [RD]
    const float* __restrict__ cent,   // [NE, RD]
    const float* __restrict__ prior,  // [NE]
    float* __restrict__ resp_out,     // [N, NE] f32 (ws)
    float* __restrict__ loss_acc)     // [1] f32 (ws)
{
  __shared__ float lsum[4];
  const int tid  = threadIdx.x;
  const int wid  = tid >> 6;
  const int lane = tid & 63;
  const int row0 = blockIdx.x * 16 + wid * 4;

  const float* xr0 = x + (size_t)row0 * CC;
  float acc[4] = {0.f, 0.f, 0.f, 0.f};
  #pragma unroll 4
  for (int c0 = 0; c0 < CC; c0 += 4) {
    float4 wv = *(const float4*)&wT4[(c0 << 6) + (lane << 2)];  // coalesced
    #pragma unroll
    for (int r = 0; r < 4; ++r) {
      float4 xv = *(const float4*)(xr0 + r * CC + c0);          // wave-uniform
      acc[r] += xv.x * wv.x + xv.y * wv.y + xv.z * wv.z + xv.w * wv.w;
    }
  }
  const float mb = map_b[lane];
  float kk[4] = {acc[0] + mb, acc[1] + mb, acc[2] + mb, acc[3] + mb};

  float ce[8], c2[8], lp[8];
  #pragma unroll
  for (int e = 0; e < 8; ++e) {
    ce[e] = cent[e * RDIM + lane];
    float v = ce[e] * ce[e];
    #pragma unroll
    for (int off = 32; off; off >>= 1) v += __shfl_xor(v, off, 64);
    c2[e] = v;
    lp[e] = __logf(prior[e]);
  }

  float dsum = 0.f;
  #pragma unroll
  for (int r = 0; r < 4; ++r) {
    float k = kk[r];
    float v[9];
    v[0] = k * k;
    #pragma unroll
    for (int e = 0; e < 8; ++e) v[e + 1] = k * ce[e];
    #pragma unroll
    for (int off = 32; off; off >>= 1) {
      #pragma unroll
      for (int q = 0; q < 9; ++q) v[q] += __shfl_xor(v[q], off, 64);
    }
    float lr[8], mx = -3.4e38f;
    #pragma unroll
    for (int e = 0; e < 8; ++e) {
      float d2 = v[0] + c2[e] - 2.f * v[e + 1];
      lr[e] = -0.5f * d2 - LOG2PI_TERM + lp[e];
      mx = fmaxf(mx, lr[e]);
    }
    float s = 0.f;
    #pragma unroll
    for (int e = 0; e < 8; ++e) s += __expf(lr[e] - mx);
    float denom = mx + __logf(s);
    dsum += denom;
    float myv = 0.f;
    #pragma unroll
    for (int e = 0; e < 8; ++e) {
      float re = __expf(lr[e] - denom);
      myv = (lane == e) ? re : myv;
    }
    if (lane < 8) resp_out[(size_t)(row0 + r) * NE + lane] = myv;
  }
  if (lane == 0) lsum[wid] = dsum;
  __syncthreads();
  if (tid == 0) {
    float t = lsum[0] + lsum[1] + lsum[2] + lsum[3];
    atomicAdd(loss_acc, -COMMIT_SCALE * t);
  }
}

// ---------------------------------------------------------------------------
// Kernel 2: y[m,o] = sum_e resp[m,e] * sum_k x[m,k] W_e[o,k] + bias_b[o].
// ALL-REGISTER streaming GEMM. Block 256m x 64o; 4 waves each own 64m x 64o.
// No operand LDS, no per-phase barriers. Per phase (kk,e): 32 MFMA using
// register-resident af (x, packed once per kk) and B frags loaded
// global->reg one phase ahead into ping-pong buffers (parity static via
// kk-loop unroll x2). resp applied on f32 K=64 partials; e==8 (bias_w)
// accumulates via MFMA C-in. sc scale table in LDS (8KB, broadcast reads).
// Fragment gather = 16 cache lines/load = same line count as coalesced.
// ---------------------------------------------------------------------------
__global__ __launch_bounds__(256, 2) void k_moe(
    const float* __restrict__ x,             // [N, C] f32
    const unsigned short* __restrict__ wb,   // [9, O, C] bf16 (ws)
    const float* __restrict__ bb,            // [O] f32
    const float* __restrict__ resp,          // [N, NE] f32 (ws)
    const float* __restrict__ loss_acc,      // [1] f32 (ws)
    float* __restrict__ out)                 // [N*O + 1] f32
{
  __shared__ float sc[NE * 256];   // 8 KB resp scales

  const int tid = threadIdx.x;
  const int m0 = blockIdx.x * 256;
  const int o0 = blockIdx.y * 64;
  const int lane = tid & 63;
  const int wid = tid >> 6;
  const int fr = lane & 15;
  const int fq = lane >> 4;

  // resp scales: sc[e][row] (experts 0..7; e==8 needs no scale)
  for (int idx = tid; idx < 256 * NE; idx += 256) {
    int r = idx >> 3, e = idx & 7;
    sc[e * 256 + r] = resp[(size_t)(m0 + r) * NE + e];
  }
  __syncthreads();   // the ONLY barrier

  // per-lane fragment bases.
  // A frag(i,h): lane reads x[m0+wid*64+i*16+fr][kk*64 + h*32 + fq*8 ..+7]
  // B frag(j,h): lane reads wb[e][o0+j*16+fr][kk*64 + h*32 + fq*8 ..+7]
  const float* xk = x + (size_t)(m0 + wid * 64 + fr) * CC + fq * 8;
  const unsigned short* bk = wb + (size_t)(o0 + fr) * CC + fq * 8;

  const f32x4 zero4 = {0.f, 0.f, 0.f, 0.f};
  f32x4 ySum[4][4];
  #pragma unroll
  for (int i = 0; i < 4; ++i)
    #pragma unroll
    for (int j = 0; j < 4; ++j) ySum[i][j] = zero4;

  short8 af[8];          // A frags (i,h) for current kk, live over 9 experts
  short8 bA[8], bB[8];   // B frag ping-pong (j,h)

  // --- prologue: build af(kk=0); load bA = batch(kk=0, e=0) ---------------
  #pragma unroll
  for (int ip = 0; ip < 2; ++ip) {
    float4 t0[2][2], t1[2][2];
    #pragma unroll
    for (int iw = 0; iw < 2; ++iw) {
      const int i = ip * 2 + iw;
      #pragma unroll
      for (int h = 0; h < 2; ++h) {
        const float4* pp = (const float4*)(xk + i * 8192 + h * 32);
        t0[iw][h] = pp[0]; t1[iw][h] = pp[1];
      }
    }
    #pragma unroll
    for (int iw = 0; iw < 2; ++iw) {
      const int i = ip * 2 + iw;
      #pragma unroll
      for (int h = 0; h < 2; ++h) {
        uint4 w;
        w.x = pkt(t0[iw][h].x, t0[iw][h].y);
        w.y = pkt(t0[iw][h].z, t0[iw][h].w);
        w.z = pkt(t1[iw][h].x, t1[iw][h].y);
        w.w = pkt(t1[iw][h].z, t1[iw][h].w);
        af[2 * i + h] = *(short8*)&w;
      }
    }
  }
  #pragma unroll
  for (int j = 0; j < 4; ++j)
    #pragma unroll
    for (int h = 0; h < 2; ++h)
      bA[2 * j + h] = *(const short8*)(bk + j * 8192 + h * 32);

  #pragma unroll 1
  for (int kk2 = 0; kk2 < 4; ++kk2) {
    #pragma unroll
    for (int p = 0; p < 18; ++p) {         // 2 kk x 9 experts, parity static
      const int e = p % 9;
      short8* bc = (p & 1) ? bB : bA;      // consume (folds: p static)
      short8* bn = (p & 1) ? bA : bB;      // prefetch target

      // --- prefetch next phase's B frags (age one full phase) -------------
      if (e < 8) {
        #pragma unroll
        for (int j = 0; j < 4; ++j)
          #pragma unroll
          for (int h = 0; h < 2; ++h)
            bn[2 * j + h] = *(const short8*)(
                bk + (size_t)(e + 1) * 262144 + j * 8192 + h * 32);
      } else if (p == 8 || kk2 < 3) {      // next kk's e=0
        #pragma unroll
        for (int j = 0; j < 4; ++j)
          #pragma unroll
          for (int h = 0; h < 2; ++h)
            bn[2 * j + h] = *(const short8*)(bk + 64 + j * 8192 + h * 32);
      }

      // --- compute current phase ------------------------------------------
      if (e < 8) {
        f32x4 si[4];
        #pragma unroll
        for (int i = 0; i < 4; ++i)
          si[i] = *(const f32x4*)&sc[e * 256 + wid * 64 + i * 16 + fq * 4];
        #pragma unroll
        for (int i = 0; i < 4; ++i)
          #pragma unroll
          for (int j = 0; j < 4; ++j) {
            f32x4 t = __builtin_amdgcn_mfma_f32_16x16x32_bf16(
                af[2 * i], bc[2 * j], zero4, 0, 0, 0);
            t = __builtin_amdgcn_mfma_f32_16x16x32_bf16(
                af[2 * i + 1], bc[2 * j + 1], t, 0, 0, 0);
            ySum[i][j] += si[i] * t;
          }
      } else {
        // bias_w expert, scale 1.0: accumulate via MFMA C-in
        #pragma unroll
        for (int i = 0; i < 4; ++i)
          #pragma unroll
          for (int j = 0; j < 4; ++j) {
            ySum[i][j] = __builtin_amdgcn_mfma_f32_16x16x32_bf16(
                af[2 * i], bc[2 * j], ySum[i][j], 0, 0, 0);
            ySum[i][j] = __builtin_amdgcn_mfma_f32_16x16x32_bf16(
                af[2 * i + 1], bc[2 * j + 1], ySum[i][j], 0, 0, 0);
          }
        // rebuild af for kk+1 (af's last use was this phase's MFMAs)
        if (p == 8 || kk2 < 3) {
          #pragma unroll
          for (int ip = 0; ip < 2; ++ip) {
            float4 t0[2][2], t1[2][2];
            #pragma unroll
            for (int iw = 0; iw < 2; ++iw) {
              const int i = ip * 2 + iw;
              #pragma unroll
              for (int h = 0; h < 2; ++h) {
                const float4* pp = (const float4*)(xk + 64 + i * 8192 + h * 32);
                t0[iw][h] = pp[0]; t1[iw][h] = pp[1];
              }
            }
            #pragma unroll
            for (int iw = 0; iw < 2; ++iw) {
              const int i = ip * 2 + iw;
              #pragma unroll
              for (int h = 0; h < 2; ++h) {
                uint4 w;
                w.x = pkt(t0[iw][h].x, t0[iw][h].y);
                w.y = pkt(t0[iw][h].z, t0[iw][h].w);
                w.z = pkt(t1[iw][h].x, t1[iw][h].y);
                w.w = pkt(t1[iw][h].z, t1[iw][h].w);
                af[2 * i + h] = *(short8*)&w;
              }
            }
          }
          xk += 64;
        }
        bk += 64;   // advance B base to next kk
      }
    }
  }

  // epilogue: + bias_b, store f32
  #pragma unroll
  for (int j = 0; j < 4; ++j) {
    const int o = o0 + j * 16 + fr;
    const float bias = bb[o];
    #pragma unroll
    for (int i = 0; i < 4; ++i) {
      #pragma unroll
      for (int r = 0; r < 4; ++r) {
        int m = m0 + wid * 64 + i * 16 + fq * 4 + r;
        out[(size_t)m * OO + o] = ySum[i][j][r] + bias;
      }
    }
  }

  if (blockIdx.x == 0 && blockIdx.y == 0 && tid == 0)
    out[(size_t)NROWS * OO] = loss_acc[0];
}

extern "C" void kernel_launch(void* const* d_in, const int* in_sizes, int n_in,
                              void* d_out, int out_size, void* d_ws, size_t ws_size,
                              hipStream_t stream) {
  const float* x     = (const float*)d_in[0];
  // d_in[1] = key_feat (ignored by forward)
  const float* map_w = (const float*)d_in[2];
  const float* map_b = (const float*)d_in[3];
  const float* cent  = (const float*)d_in[4];
  const float* prior = (const float*)d_in[5];
  const float* pw    = (const float*)d_in[6];
  const float* bw    = (const float*)d_in[7];
  const float* bb    = (const float*)d_in[8];
  float* out = (float*)d_out;

  char* wsp = (char*)d_ws;
  float* resp = (float*)wsp;                              // 524288 B
  float* loss = (float*)(wsp + 524288);                   // 16 B slot
  unsigned short* wb = (unsigned short*)(wsp + 524304);   // 4718592 B
  float* wT4 = (float*)(wsp + 524304 + 4718592);          // 131072 B

  hipMemsetAsync(loss, 0, sizeof(float), stream);
  k_prep<<<dim3(NCV + TB), dim3(256), 0, stream>>>(pw, bw, map_w, wb, wT4);
  k_assign<<<dim3(NROWS / 16), dim3(256), 0, stream>>>(x, wT4, map_b, cent, prior, resp, loss);
  dim3 grid(NROWS / 256, OO / 64);
  k_moe<<<grid, dim3(256), 0, stream>>>(x, wb, bb, resp, loss, out);
}

// Round 10
// 440.291 us; speedup vs baseline: 2.6365x; 2.6365x over previous
//
#include <hip/hip_runtime.h>
#include <hip/hip_bf16.h>

// Problem constants (T=2048, B=8, C=512, O=512, RD=64, NE=8, tau=1, commit=0.1)
// Ledger: r0 structure closes at 144 phases x ~2000cyc (LDS ~770 + MFMA 515 +
// drain ~500). r8/r10/r11/r14/r15 all moved cost between buckets, never
// removed one. r16 (all-register) died of rule #20: `(p&1)? bB : bA` pointer
// select -> arrays in scratch -> 1.65GB spill writes (VGPR=128, 995us).
// Round-17: all-register streaming GEMM, scratch-proofed. No LDS AT ALL, no
// barriers: waves free-run. resp folded into A in-register (VALU mul+pkt,
// hides under MFMA); B frags global->reg (16-line gather, per-wave-private,
// L1-served); ping-pong via NAMED variables through macro token-pasting (18
// phases statically expanded per 2-kk body; every array index is a literal).
// Math identical to verified r0 (same frag mapping, truncating pkt, raw e=8).
#define NROWS 16384
#define CC 512
#define OO 512
#define RDIM 64
#define NE 8
#define NEXP 9            // 8 experts + bias_w as expert 8 (scale 1.0)
#define COMMIT_SCALE 0.1f
#define LOG2PI_TERM 58.81206612509905f   // (RD/2)*log(2*pi*tau), tau=1

typedef __attribute__((ext_vector_type(8))) short short8;
typedef __attribute__((ext_vector_type(4))) float f32x4;

__device__ __forceinline__ unsigned short f2bf(float f) {
  unsigned int u = __float_as_uint(f);
  u += 0x7fffu + ((u >> 16) & 1u);   // round-to-nearest-even
  return (unsigned short)(u >> 16);
}
// truncating pack: [hi16(b) | hi16(a)]
__device__ __forceinline__ unsigned int pkt(float a, float b) {
  return (__float_as_uint(b) & 0xffff0000u) | (__float_as_uint(a) >> 16);
}

// ---------------------------------------------------------------------------
// Kernel 0: f32->bf16 copy of [pw_w ; bias_w] -> wb; transpose map_w -> wT4.
// ---------------------------------------------------------------------------
#define P4 524288u    // pw_w float4 count   (2097152 / 4)
#define B4 65536u     // bias_w float4 count (262144 / 4)
#define NCV ((P4 + B4) / 256u)        // 2304 convert blocks
#define TB 128u                        // 32768 map_w elems / 256

__global__ __launch_bounds__(256) void k_prep(
    const float* __restrict__ pw, const float* __restrict__ bw,
    const float* __restrict__ mw,
    unsigned short* __restrict__ wb, float* __restrict__ wT4)
{
  unsigned int b = blockIdx.x;
  if (b >= NCV) {   // map_w transpose: i indexes map_w[j*512+c]
    unsigned int i = (b - NCV) * 256 + threadIdx.x;
    unsigned int j = i >> 9, c = i & 511u;
    wT4[((c >> 2) << 8) + (j << 2) + (c & 3u)] = mw[i];
    return;
  }
  unsigned int i = b * 256 + threadIdx.x;   // float4 index into [pw|bw]
  const float* src = (i < P4) ? (pw + (size_t)i * 4)
                              : (bw + (size_t)(i - P4) * 4);
  unsigned short* dst = wb + (size_t)i * 4;
  float4 v = *(const float4*)src;
  ushort4 o;
  o.x = f2bf(v.x); o.y = f2bf(v.y); o.z = f2bf(v.z); o.w = f2bf(v.w);
  *(ushort4*)dst = o;
}

// ---------------------------------------------------------------------------
// Kernel 1: GMM responsibilities + loss (pure f32).
// ---------------------------------------------------------------------------
__global__ __launch_bounds__(256) void k_assign(
    const float* __restrict__ x,      // [N, C]
    const float* __restrict__ wT4,    // [C/4, 64, 4] transposed map_w
    const float* __restrict__ map_b,  // [RD]
    const float* __restrict__ cent,   // [NE, RD]
    const float* __restrict__ prior,  // [NE]
    float* __restrict__ resp_out,     // [N, NE] f32 (ws)
    float* __restrict__ loss_acc)     // [1] f32 (ws)
{
  __shared__ float lsum[4];
  const int tid  = threadIdx.x;
  const int wid  = tid >> 6;
  const int lane = tid & 63;
  const int row0 = blockIdx.x * 16 + wid * 4;

  const float* xr0 = x + (size_t)row0 * CC;
  float acc[4] = {0.f, 0.f, 0.f, 0.f};
  #pragma unroll 4
  for (int c0 = 0; c0 < CC; c0 += 4) {
    float4 wv = *(const float4*)&wT4[(c0 << 6) + (lane << 2)];  // coalesced
    #pragma unroll
    for (int r = 0; r < 4; ++r) {
      float4 xv = *(const float4*)(xr0 + r * CC + c0);          // wave-uniform
      acc[r] += xv.x * wv.x + xv.y * wv.y + xv.z * wv.z + xv.w * wv.w;
    }
  }
  const float mb = map_b[lane];
  float kk[4] = {acc[0] + mb, acc[1] + mb, acc[2] + mb, acc[3] + mb};

  float ce[8], c2[8], lp[8];
  #pragma unroll
  for (int e = 0; e < 8; ++e) {
    ce[e] = cent[e * RDIM + lane];
    float v = ce[e] * ce[e];
    #pragma unroll
    for (int off = 32; off; off >>= 1) v += __shfl_xor(v, off, 64);
    c2[e] = v;
    lp[e] = __logf(prior[e]);
  }

  float dsum = 0.f;
  #pragma unroll
  for (int r = 0; r < 4; ++r) {
    float k = kk[r];
    float v[9];
    v[0] = k * k;
    #pragma unroll
    for (int e = 0; e < 8; ++e) v[e + 1] = k * ce[e];
    #pragma unroll
    for (int off = 32; off; off >>= 1) {
      #pragma unroll
      for (int q = 0; q < 9; ++q) v[q] += __shfl_xor(v[q], off, 64);
    }
    float lr[8], mx = -3.4e38f;
    #pragma unroll
    for (int e = 0; e < 8; ++e) {
      float d2 = v[0] + c2[e] - 2.f * v[e + 1];
      lr[e] = -0.5f * d2 - LOG2PI_TERM + lp[e];
      mx = fmaxf(mx, lr[e]);
    }
    float s = 0.f;
    #pragma unroll
    for (int e = 0; e < 8; ++e) s += __expf(lr[e] - mx);
    float denom = mx + __logf(s);
    dsum += denom;
    float myv = 0.f;
    #pragma unroll
    for (int e = 0; e < 8; ++e) {
      float re = __expf(lr[e] - denom);
      myv = (lane == e) ? re : myv;
    }
    if (lane < 8) resp_out[(size_t)(row0 + r) * NE + lane] = myv;
  }
  if (lane == 0) lsum[wid] = dsum;
  __syncthreads();
  if (tid == 0) {
    float t = lsum[0] + lsum[1] + lsum[2] + lsum[3];
    atomicAdd(loss_acc, -COMMIT_SCALE * t);
  }
}

// ---------------------------------------------------------------------------
// Kernel 2: y[m,o] = sum_e resp[m,e] * sum_k x[m,k] W_e[o,k] + bias_b[o].
// ZERO-LDS, ZERO-BARRIER streaming GEMM. Block 128m x 128o; 4 waves, each
// 64m x 64o (wm=(wid&1)*64, wn=(wid>>1)*64). Per phase (kk,e): build scaled
// A-frags in-register (sv[i][e] * xc, truncating pkt) and 16 MFMA (C-in
// accumulate, resp folded -> no epilogue scale, no sc table). B frags load
// global->reg (1 dwordx4 per frag, 16-line gather), ping-pong pA*/pB* as
// NAMED vars via token pasting; 9-phase parity handled by 2-kk body macro.
// e==8 uses raw-packed x (scale 1.0). x f32 slice (xc) reloaded during e==8.
// ---------------------------------------------------------------------------
#define MFm(A,B,C) __builtin_amdgcn_mfma_f32_16x16x32_bf16((A),(B),(C),0,0,0)

#define BLOAD(D, EOFF) do {                                         \
    D##0 = *(const short8*)(bkb + (EOFF));                          \
    D##1 = *(const short8*)(bkb + (EOFF) + 8192);                   \
    D##2 = *(const short8*)(bkb + (EOFF) + 16384);                  \
    D##3 = *(const short8*)(bkb + (EOFF) + 24576);                  \
  } while (0)

#define AROW(II, EE, B_) do {                                       \
    const float s_ = sv[II][EE];                                    \
    uint4 w_;                                                       \
    w_.x = pkt(xc[II][0].x * s_, xc[II][0].y * s_);                 \
    w_.y = pkt(xc[II][0].z * s_, xc[II][0].w * s_);                 \
    w_.z = pkt(xc[II][1].x * s_, xc[II][1].y * s_);                 \
    w_.w = pkt(xc[II][1].z * s_, xc[II][1].w * s_);                 \
    const short8 a_ = *(const short8*)&w_;                          \
    acc[II][0] = MFm(a_, B_##0, acc[II][0]);                        \
    acc[II][1] = MFm(a_, B_##1, acc[II][1]);                        \
    acc[II][2] = MFm(a_, B_##2, acc[II][2]);                        \
    acc[II][3] = MFm(a_, B_##3, acc[II][3]);                        \
  } while (0)

#define PH(EE, B_) do {                                             \
    AROW(0, EE, B_); AROW(1, EE, B_);                               \
    AROW(2, EE, B_); AROW(3, EE, B_);                               \
  } while (0)

#define ARAWV(II) do {                                              \
    uint4 w_;                                                       \
    w_.x = pkt(xc[II][0].x, xc[II][0].y);                           \
    w_.y = pkt(xc[II][0].z, xc[II][0].w);                           \
    w_.z = pkt(xc[II][1].x, xc[II][1].y);                           \
    w_.w = pkt(xc[II][1].z, xc[II][1].w);                           \
    ar##II = *(const short8*)&w_;                                   \
  } while (0)

#define XNEXT(II) do {                                              \
    xc[II][0] = *(const float4*)(xp##II + 32);                      \
    xc[II][1] = *(const float4*)(xp##II + 36);                      \
    xp##II += 32;                                                   \
  } while (0)

// e==8 phase: raw frags from CURRENT xc, then (unless LAST) reload xc(kk+1)
// and prefetch B(kk+1, e=0) into BN, then the 16 accumulating MFMAs.
#define PH8(BC, BN, LAST) do {                                      \
    short8 ar0, ar1, ar2, ar3;                                      \
    ARAWV(0); ARAWV(1); ARAWV(2); ARAWV(3);                         \
    if (!(LAST)) {                                                  \
      XNEXT(0); XNEXT(1); XNEXT(2); XNEXT(3);                       \
      BLOAD(BN, 32);                                                \
      bkb += 32;                                                    \
    }                                                               \
    acc[0][0] = MFm(ar0, BC##0, acc[0][0]);                         \
    acc[0][1] = MFm(ar0, BC##1, acc[0][1]);                         \
    acc[0][2] = MFm(ar0, BC##2, acc[0][2]);                         \
    acc[0][3] = MFm(ar0, BC##3, acc[0][3]);                         \
    acc[1][0] = MFm(ar1, BC##0, acc[1][0]);                         \
    acc[1][1] = MFm(ar1, BC##1, acc[1][1]);                         \
    acc[1][2] = MFm(ar1, BC##2, acc[1][2]);                         \
    acc[1][3] = MFm(ar1, BC##3, acc[1][3]);                         \
    acc[2][0] = MFm(ar2, BC##0, acc[2][0]);                         \
    acc[2][1] = MFm(ar2, BC##1, acc[2][1]);                         \
    acc[2][2] = MFm(ar2, BC##2, acc[2][2]);                         \
    acc[2][3] = MFm(ar2, BC##3, acc[2][3]);                         \
    acc[3][0] = MFm(ar3, BC##0, acc[3][0]);                         \
    acc[3][1] = MFm(ar3, BC##1, acc[3][1]);                         \
    acc[3][2] = MFm(ar3, BC##2, acc[3][2]);                         \
    acc[3][3] = MFm(ar3, BC##3, acc[3][3]);                         \
  } while (0)

// One kk: e0..e8; PA_ holds e0 on entry. Prefetch e+1 into the idle buffer,
// consume e from the live one. On exit the NEXT kk's e0 sits in PB_.
#define KKBODY(PA_, PB_, LAST) do {                                 \
    BLOAD(PB_, 262144);       PH(0, PA_);                           \
    BLOAD(PA_, 2 * 262144);   PH(1, PB_);                           \
    BLOAD(PB_, 3 * 262144);   PH(2, PA_);                           \
    BLOAD(PA_, 4 * 262144);   PH(3, PB_);                           \
    BLOAD(PB_, 5 * 262144);   PH(4, PA_);                           \
    BLOAD(PA_, 6 * 262144);   PH(5, PB_);                           \
    BLOAD(PB_, 7 * 262144);   PH(6, PA_);                           \
    BLOAD(PA_, 8 * 262144);   PH(7, PB_);                           \
    PH8(PA_, PB_, LAST);                                            \
  } while (0)

__global__ __launch_bounds__(256, 2) void k_moe(
    const float* __restrict__ x,             // [N, C] f32
    const unsigned short* __restrict__ wb,   // [9, O, C] bf16 (ws)
    const float* __restrict__ bb,            // [O] f32
    const float* __restrict__ resp,          // [N, NE] f32 (ws)
    const float* __restrict__ loss_acc,      // [1] f32 (ws)
    float* __restrict__ out)                 // [N*O + 1] f32
{
  const int tid = threadIdx.x;
  const int m0 = blockIdx.x * 128;
  const int o0 = blockIdx.y * 128;
  const int lane = tid & 63;
  const int wid = tid >> 6;
  const int wm = (wid & 1) * 64;
  const int wn = (wid >> 1) * 64;
  const int fr = lane & 15;
  const int fq = lane >> 4;

  // B fragment base: row (o0+wn+fr), cols fq*8; row j*16 -> +8192 shorts.
  const unsigned short* bkb = wb + (size_t)(o0 + wn + fr) * CC + fq * 8;

  // x row pointers for the wave's 4 m-fragment rows (advance +32 per kk).
  const float* xp0 = x + (size_t)(m0 + wm +  0 + fr) * CC + fq * 8;
  const float* xp1 = x + (size_t)(m0 + wm + 16 + fr) * CC + fq * 8;
  const float* xp2 = x + (size_t)(m0 + wm + 32 + fr) * CC + fq * 8;
  const float* xp3 = x + (size_t)(m0 + wm + 48 + fr) * CC + fq * 8;

  // resp scales for this lane's 4 rows x 8 experts (registers, static idx).
  float sv[4][8];
  {
    const float* rp = resp + (size_t)(m0 + wm + fr) * NE;
    #define SVLOAD(II)                                              \
      { float4 lo_ = *(const float4*)(rp + (II) * 128);             \
        float4 hi_ = *(const float4*)(rp + (II) * 128 + 4);         \
        sv[II][0] = lo_.x; sv[II][1] = lo_.y;                       \
        sv[II][2] = lo_.z; sv[II][3] = lo_.w;                       \
        sv[II][4] = hi_.x; sv[II][5] = hi_.y;                       \
        sv[II][6] = hi_.z; sv[II][7] = hi_.w; }
    SVLOAD(0) SVLOAD(1) SVLOAD(2) SVLOAD(3)
    #undef SVLOAD
  }

  // x f32 slice for current kk (kk=0), 8 floats per fragment row.
  float4 xc[4][2];
  xc[0][0] = *(const float4*)xp0; xc[0][1] = *(const float4*)(xp0 + 4);
  xc[1][0] = *(const float4*)xp1; xc[1][1] = *(const float4*)(xp1 + 4);
  xc[2][0] = *(const float4*)xp2; xc[2][1] = *(const float4*)(xp2 + 4);
  xc[3][0] = *(const float4*)xp3; xc[3][1] = *(const float4*)(xp3 + 4);

  f32x4 acc[4][4];
  #pragma unroll
  for (int i = 0; i < 4; ++i)
    #pragma unroll
    for (int j = 0; j < 4; ++j) {
      f32x4 z = {0.f, 0.f, 0.f, 0.f};
      acc[i][j] = z;
    }

  short8 pA0, pA1, pA2, pA3;   // B ping buffer
  short8 pB0, pB1, pB2, pB3;   // B pong buffer
  BLOAD(pA, 0);                // (kk=0, e=0)

  #pragma unroll 1
  for (int kk2 = 0; kk2 < 8; ++kk2) {
    KKBODY(pA, pB, 0);
    KKBODY(pB, pA, (kk2 == 7));
  }

  // epilogue: + bias_b, store f32 (resp already folded into A).
  #pragma unroll
  for (int j = 0; j < 4; ++j) {
    const int o = o0 + wn + j * 16 + fr;
    const float bias = bb[o];
    #pragma unroll
    for (int i = 0; i < 4; ++i) {
      #pragma unroll
      for (int r = 0; r < 4; ++r) {
        int m = m0 + wm + i * 16 + fq * 4 + r;
        out[(size_t)m * OO + o] = acc[i][j][r] + bias;
      }
    }
  }

  if (blockIdx.x == 0 && blockIdx.y == 0 && tid == 0)
    out[(size_t)NROWS * OO] = loss_acc[0];
}

extern "C" void kernel_launch(void* const* d_in, const int* in_sizes, int n_in,
                              void* d_out, int out_size, void* d_ws, size_t ws_size,
                              hipStream_t stream) {
  const float* x     = (const float*)d_in[0];
  // d_in[1] = key_feat (ignored by forward)
  const float* map_w = (const float*)d_in[2];
  const float* map_b = (const float*)d_in[3];
  const float* cent  = (const float*)d_in[4];
  const float* prior = (const float*)d_in[5];
  const float* pw    = (const float*)d_in[6];
  const float* bw    = (const float*)d_in[7];
  const float* bb    = (const float*)d_in[8];
  float* out = (float*)d_out;

  char* wsp = (char*)d_ws;
  float* resp = (float*)wsp;                              // 524288 B
  float* loss = (float*)(wsp + 524288);                   // 16 B slot
  unsigned short* wb = (unsigned short*)(wsp + 524304);   // 4718592 B
  float* wT4 = (float*)(wsp + 524304 + 4718592);          // 131072 B

  hipMemsetAsync(loss, 0, sizeof(float), stream);
  k_prep<<<dim3(NCV + TB), dim3(256), 0, stream>>>(pw, bw, map_w, wb, wT4);
  k_assign<<<dim3(NROWS / 16), dim3(256), 0, stream>>>(x, wT4, map_b, cent, prior, resp, loss);
  dim3 grid(NROWS / 128, OO / 128);
  k_moe<<<grid, dim3(256), 0, stream>>>(x, wb, bb, resp, loss, out);
}

// Round 11
// 296.768 us; speedup vs baseline: 3.9116x; 1.4836x over previous
//
#include <hip/hip_runtime.h>
#include <hip/hip_bf16.h>

// Problem constants (T=2048, B=8, C=512, O=512, RD=64, NE=8, tau=1, commit=0.1)
// Ledger: r8 LDS fix (neutral), r10 XCD remap (slower), r11 counted-vmcnt
// (slower), r14/r15 occupancy (spill / slower), r16/r17 zero-LDS (spill x2).
// Scheduling levers exhausted -> algebraic reduction instead.
// Round-18: BIAS FOLD. resp is a softmax => sum_e resp[m,e] == 1, so
//   y = sum_e resp_e (x W_e^T) + x B^T  ==  sum_e resp_e (x (W_e+B)^T).
// k_prep writes wb[e] = bf16(pw[e] + bias_w) (8 experts, no 9th pass);
// k_moe = round-2-verified structure with NEXP=8: 64 phases instead of 72
// (-11% MFMA, -11% B traffic, -11% barriers). Everything else untouched.
#define NROWS 16384
#define CC 512
#define OO 512
#define RDIM 64
#define NE 8
#define NEXP 8            // bias_w folded into every expert (sum resp = 1)
#define COMMIT_SCALE 0.1f
#define LOG2PI_TERM 58.81206612509905f   // (RD/2)*log(2*pi*tau), tau=1

typedef __attribute__((ext_vector_type(8))) short short8;
typedef __attribute__((ext_vector_type(4))) float f32x4;

__device__ __forceinline__ unsigned short f2bf(float f) {
  unsigned int u = __float_as_uint(f);
  u += 0x7fffu + ((u >> 16) & 1u);   // round-to-nearest-even
  return (unsigned short)(u >> 16);
}
// truncating pack: [hi16(b) | hi16(a)]
__device__ __forceinline__ unsigned int pkt(float a, float b) {
  return (__float_as_uint(b) & 0xffff0000u) | (__float_as_uint(a) >> 16);
}

__device__ __forceinline__ void gl_lds16(const unsigned short* g, unsigned short* l) {
  __builtin_amdgcn_global_load_lds(
      (const __attribute__((address_space(1))) void*)g,
      (__attribute__((address_space(3))) void*)l, 16, 0, 0);
}

// ---------------------------------------------------------------------------
// Kernel 0: wb[e] = bf16(pw[e] + bias_w)  (bias fold); transpose map_w -> wT4.
// ---------------------------------------------------------------------------
#define PW4 524288u   // pw float4 count (8*512*512 / 4)
#define OC4 65536u    // float4 per expert (512*512 / 4), pow2
#define NCV (PW4 / 256u)              // 2048 convert blocks
#define TB 128u                        // 32768 map_w elems / 256

__global__ __launch_bounds__(256) void k_prep(
    const float* __restrict__ pw, const float* __restrict__ bw,
    const float* __restrict__ mw,
    unsigned short* __restrict__ wb, float* __restrict__ wT4)
{
  unsigned int b = blockIdx.x;
  if (b >= NCV) {   // map_w transpose: i indexes map_w[j*512+c]
    unsigned int i = (b - NCV) * 256 + threadIdx.x;
    unsigned int j = i >> 9, c = i & 511u;
    wT4[((c >> 2) << 8) + (j << 2) + (c & 3u)] = mw[i];
    return;
  }
  unsigned int i = b * 256 + threadIdx.x;   // float4 index into pw
  unsigned int oc = i & (OC4 - 1u);         // float4 index within [O,C]
  float4 v = *(const float4*)(pw + (size_t)i * 4);
  float4 bv = *(const float4*)(bw + (size_t)oc * 4);
  ushort4 o;
  o.x = f2bf(v.x + bv.x); o.y = f2bf(v.y + bv.y);
  o.z = f2bf(v.z + bv.z); o.w = f2bf(v.w + bv.w);
  *(ushort4*)(wb + (size_t)i * 4) = o;
}

// ---------------------------------------------------------------------------
// Kernel 1: GMM responsibilities + loss (pure f32).
// ---------------------------------------------------------------------------
__global__ __launch_bounds__(256) void k_assign(
    const float* __restrict__ x,      // [N, C]
    const float* __restrict__ wT4,    // [C/4, 64, 4] transposed map_w
    const float* __restrict__ map_b,  // [RD]
    const float* __restrict__ cent,   // [NE, RD]
    const float* __restrict__ prior,  // [NE]
    float* __restrict__ resp_out,     // [N, NE] f32 (ws)
    float* __restrict__ loss_acc)     // [1] f32 (ws)
{
  __shared__ float lsum[4];
  const int tid  = threadIdx.x;
  const int wid  = tid >> 6;
  const int lane = tid & 63;
  const int row0 = blockIdx.x * 16 + wid * 4;

  const float* xr0 = x + (size_t)row0 * CC;
  float acc[4] = {0.f, 0.f, 0.f, 0.f};
  #pragma unroll 4
  for (int c0 = 0; c0 < CC; c0 += 4) {
    float4 wv = *(const float4*)&wT4[(c0 << 6) + (lane << 2)];  // coalesced
    #pragma unroll
    for (int r = 0; r < 4; ++r) {
      float4 xv = *(const float4*)(xr0 + r * CC + c0);          // wave-uniform
      acc[r] += xv.x * wv.x + xv.y * wv.y + xv.z * wv.z + xv.w * wv.w;
    }
  }
  const float mb = map_b[lane];
  float kk[4] = {acc[0] + mb, acc[1] + mb, acc[2] + mb, acc[3] + mb};

  float ce[8], c2[8], lp[8];
  #pragma unroll
  for (int e = 0; e < 8; ++e) {
    ce[e] = cent[e * RDIM + lane];
    float v = ce[e] * ce[e];
    #pragma unroll
    for (int off = 32; off; off >>= 1) v += __shfl_xor(v, off, 64);
    c2[e] = v;
    lp[e] = __logf(prior[e]);
  }

  float dsum = 0.f;
  #pragma unroll
  for (int r = 0; r < 4; ++r) {
    float k = kk[r];
    float v[9];
    v[0] = k * k;
    #pragma unroll
    for (int e = 0; e < 8; ++e) v[e + 1] = k * ce[e];
    #pragma unroll
    for (int off = 32; off; off >>= 1) {
      #pragma unroll
      for (int q = 0; q < 9; ++q) v[q] += __shfl_xor(v[q], off, 64);
    }
    float lr[8], mx = -3.4e38f;
    #pragma unroll
    for (int e = 0; e < 8; ++e) {
      float d2 = v[0] + c2[e] - 2.f * v[e + 1];
      lr[e] = -0.5f * d2 - LOG2PI_TERM + lp[e];
      mx = fmaxf(mx, lr[e]);
    }
    float s = 0.f;
    #pragma unroll
    for (int e = 0; e < 8; ++e) s += __expf(lr[e] - mx);
    float denom = mx + __logf(s);
    dsum += denom;
    float myv = 0.f;
    #pragma unroll
    for (int e = 0; e < 8; ++e) {
      float re = __expf(lr[e] - denom);
      myv = (lane == e) ? re : myv;
    }
    if (lane < 8) resp_out[(size_t)(row0 + r) * NE + lane] = myv;
  }
  if (lane == 0) lsum[wid] = dsum;
  __syncthreads();
  if (tid == 0) {
    float t = lsum[0] + lsum[1] + lsum[2] + lsum[3];
    atomicAdd(loss_acc, -COMMIT_SCALE * t);
  }
}

// ---------------------------------------------------------------------------
// Kernel 2: y[m,o] = sum_e resp[m,e] * sum_k x[m,k] W'_e[o,k] + bias_b[o],
// where W'_e = W_e + bias_w (folded at prep; sum_e resp = 1).
// 128x128 block tile, BK=64, kk-outer / e-inner (8 experts). A = raw bf16(x),
// staged once per kk, fragments register-resident across the 8 experts; resp
// applied on the f32 K=64 partial (ySum += s*t). Wave tile 128x32 (self-
// staged B panels). XOR chunk swizzle -> conflict-free b128. ONE barrier per
// phase; next B gl_lds issued right after it. [round-2-verified structure]
// ---------------------------------------------------------------------------
__global__ __launch_bounds__(256, 2) void k_moe(
    const float* __restrict__ x,             // [N, C] f32
    const unsigned short* __restrict__ wb,   // [8, O, C] bf16 (ws)
    const float* __restrict__ bb,            // [O] f32
    const float* __restrict__ resp,          // [N, NE] f32 (ws)
    const float* __restrict__ loss_acc,      // [1] f32 (ws)
    float* __restrict__ out)                 // [N*O + 1] f32
{
  __shared__ __align__(16) unsigned short aT[128 * 64];       // 16 KB
  __shared__ __align__(16) unsigned short bT[2][128 * 64];    // 32 KB dbuf
  __shared__ float sc[NE * 128];                              // 4 KB resp

  const int tid = threadIdx.x;
  const int m0 = blockIdx.x * 128;
  const int o0 = blockIdx.y * 128;
  const int lane = tid & 63;
  const int wid = tid >> 6;
  const int fr = lane & 15;
  const int fq = lane >> 4;

  // resp scales: sc[e][row]
  for (int idx = tid; idx < 128 * NE; idx += 256) {
    int r = idx >> 3, e = idx & 7;
    sc[e * 128 + r] = resp[(size_t)(m0 + r) * NE + e];
  }

  // --- B staging map (gl_lds, inverse-swizzled global source) -------------
  // wave wid stages rows [wid*32, wid*32+32): call q covers rows +q*8+rl,
  // lane puts LDS chunk slot (l&7); fetches global chunk (l&7)^rl so that
  // LDS slot (row, c) holds global chunk c ^ (row&7).
  const int rl = lane >> 3;
  const int ch = lane & 7;
  const unsigned short* wb_t =
      wb + (size_t)(o0 + wid * 32 + rl) * CC + (ch ^ rl) * 8;

  // --- A pack map (ds_write to swizzled slots) ----------------------------
  const int ar = tid >> 1;          // row 0..127
  const int ah = tid & 1;           // chunk half: chunks ah*4 .. ah*4+3
  const float* xa = x + (size_t)(m0 + ar) * CC + ah * 32;

  // --- fragment read offsets (shorts) -------------------------------------
  // logical chunk h*4+fq at row r lives at slot (h*4+fq)^(r&7); r&7 == fr&7.
  const int s7 = fr & 7;
  const int ac0 = (fq ^ s7) * 8;    // h=0 chunk offset; h=1: ac0 ^ 32

  const f32x4 zero4 = {0.f, 0.f, 0.f, 0.f};
  f32x4 ySum[8][2];
  #pragma unroll
  for (int i = 0; i < 8; ++i) {
    ySum[i][0] = zero4; ySum[i][1] = zero4;
  }

  // --- prologue: pack A[kk=0]; gl_lds B[kk=0][e=0] into bT[0] -------------
  {
    const float4* xp = (const float4*)xa;
    #pragma unroll
    for (int q = 0; q < 4; ++q) {
      float4 f0 = xp[2 * q], f1 = xp[2 * q + 1];
      uint4 w;
      w.x = pkt(f0.x, f0.y); w.y = pkt(f0.z, f0.w);
      w.z = pkt(f1.x, f1.y); w.w = pkt(f1.z, f1.w);
      *(uint4*)&aT[ar * 64 + (((ah * 4 + q) ^ (ar & 7)) << 3)] = w;
    }
    #pragma unroll
    for (int q = 0; q < 4; ++q)
      gl_lds16(wb_t + q * 4096, &bT[0][wid * 2048 + q * 512]);
  }

  short8 af[16];     // A fragments for current kk, live across the 8 experts
  float4 xf[8];      // x f32 prefetch for next kk's A pack
  int cur = 0;

  #pragma unroll 1
  for (int kk = 0; kk < 8; ++kk) {
    #pragma unroll 1
    for (int e = 0; e < NEXP; ++e) {
      __syncthreads();   // A[cur],B[cur] complete; prev readers of [nxt] done

      // stage NEXT phase's B (aged a full MFMA block at the next drain)
      if (e < 7 || kk < 7) {
        const int ne = (e < 7) ? e + 1 : 0;
        const int nk = (e < 7) ? kk : kk + 1;
        const unsigned short* bn = wb_t + ((size_t)ne << 18) + nk * 64;
        #pragma unroll
        for (int q = 0; q < 4; ++q)
          gl_lds16(bn + q * 4096, &bT[cur ^ 1][wid * 2048 + q * 512]);
      }

      if (e == 0) {
        // load A fragments for this kk (reused by all 8 experts)
        #pragma unroll
        for (int i = 0; i < 8; ++i) {
          const int rb = (i * 16 + fr) * 64;
          af[2 * i]     = *(const short8*)&aT[rb + ac0];
          af[2 * i + 1] = *(const short8*)&aT[rb + (ac0 ^ 32)];
        }
        if (kk < 7) {          // issue x f32 prefetch for kk+1
          const float4* xp = (const float4*)(xa + (kk + 1) * 64);
          #pragma unroll
          for (int q = 0; q < 8; ++q) xf[q] = xp[q];
        }
      } else if (e == 1 && kk < 7) {
        // pack A[kk+1] into aT (reads of aT finished at e==0, barrier since)
        #pragma unroll
        for (int q = 0; q < 4; ++q) {
          uint4 w;
          w.x = pkt(xf[2 * q].x,     xf[2 * q].y);
          w.y = pkt(xf[2 * q].z,     xf[2 * q].w);
          w.z = pkt(xf[2 * q + 1].x, xf[2 * q + 1].y);
          w.w = pkt(xf[2 * q + 1].z, xf[2 * q + 1].w);
          *(uint4*)&aT[ar * 64 + (((ah * 4 + q) ^ (ar & 7)) << 3)] = w;
        }
      }

      // B fragments for this (kk, e): wave's own 32-o panel, no duplication
      short8 bfv[4];
      const unsigned short* bc = &bT[cur][0];
      #pragma unroll
      for (int j = 0; j < 2; ++j) {
        const int rb = (wid * 32 + j * 16 + fr) * 64;
        bfv[2 * j]     = *(const short8*)&bc[rb + ac0];
        bfv[2 * j + 1] = *(const short8*)&bc[rb + (ac0 ^ 32)];
      }

      // resp-scaled accumulate (bias folded into W'_e; sum_e resp = 1)
      #pragma unroll
      for (int i = 0; i < 8; ++i) {
        const f32x4 s = *(const f32x4*)&sc[e * 128 + i * 16 + fq * 4];
        #pragma unroll
        for (int j = 0; j < 2; ++j) {
          f32x4 t = __builtin_amdgcn_mfma_f32_16x16x32_bf16(
              af[2 * i], bfv[2 * j], zero4, 0, 0, 0);
          t = __builtin_amdgcn_mfma_f32_16x16x32_bf16(
              af[2 * i + 1], bfv[2 * j + 1], t, 0, 0, 0);
          ySum[i][j] += s * t;
        }
      }
      cur ^= 1;
    }
  }

  // epilogue: + bias_b, store f32
  #pragma unroll
  for (int j = 0; j < 2; ++j) {
    const int o = o0 + wid * 32 + j * 16 + fr;
    const float bias = bb[o];
    #pragma unroll
    for (int i = 0; i < 8; ++i) {
      #pragma unroll
      for (int r = 0; r < 4; ++r) {
        int m = m0 + i * 16 + fq * 4 + r;
        out[(size_t)m * OO + o] = ySum[i][j][r] + bias;
      }
    }
  }

  if (blockIdx.x == 0 && blockIdx.y == 0 && tid == 0)
    out[(size_t)NROWS * OO] = loss_acc[0];
}

extern "C" void kernel_launch(void* const* d_in, const int* in_sizes, int n_in,
                              void* d_out, int out_size, void* d_ws, size_t ws_size,
                              hipStream_t stream) {
  const float* x     = (const float*)d_in[0];
  // d_in[1] = key_feat (ignored by forward)
  const float* map_w = (const float*)d_in[2];
  const float* map_b = (const float*)d_in[3];
  const float* cent  = (const float*)d_in[4];
  const float* prior = (const float*)d_in[5];
  const float* pw    = (const float*)d_in[6];
  const float* bw    = (const float*)d_in[7];
  const float* bb    = (const float*)d_in[8];
  float* out = (float*)d_out;

  char* wsp = (char*)d_ws;
  float* resp = (float*)wsp;                              // 524288 B
  float* loss = (float*)(wsp + 524288);                   // 16 B slot
  unsigned short* wb = (unsigned short*)(wsp + 524304);   // 4194304 B used
  float* wT4 = (float*)(wsp + 524304 + 4718592);          // 131072 B

  hipMemsetAsync(loss, 0, sizeof(float), stream);
  k_prep<<<dim3(NCV + TB), dim3(256), 0, stream>>>(pw, bw, map_w, wb, wT4);
  k_assign<<<dim3(NROWS / 16), dim3(256), 0, stream>>>(x, wT4, map_b, cent, prior, resp, loss);
  dim3 grid(NROWS / 128, OO / 128);
  k_moe<<<grid, dim3(256), 0, stream>>>(x, wb, bb, resp, loss, out);
}